// Round 9
// baseline (103.399 us; speedup 1.0000x reference)
//
#include <hip/hip_runtime.h>
#include <hip/hip_bf16.h>
#include <hip/hip_cooperative_groups.h>

namespace cg = cooperative_groups;

#define IN_FEATS 128
#define HIDDEN 32

typedef __attribute__((ext_vector_type(8))) short bf16x8;   // 8 bf16 (4 VGPRs)
typedef __attribute__((ext_vector_type(4))) float f32x4;
typedef _Float16 f16;
typedef __attribute__((ext_vector_type(2))) _Float16 f16x2;
typedef __attribute__((ext_vector_type(8))) _Float16 f16x8; // 16 B

// fp32 -> bf16 round-to-nearest-even (bit trick; NaN irrelevant for this data)
static __device__ __forceinline__ short f2bf(float f) {
    union { float f; unsigned u; } v;
    v.f = f;
    unsigned r = v.u + 0x7FFFu + ((v.u >> 16) & 1u);
    return (short)(r >> 16);
}

// ---- Phase 1 (per 16-row tile, one wave): p[tile] = fp16(h @ W1 + 0.5*b1) ----
// Verified gfx950 16x16x32 bf16 layouts (learn_hip m89/m91):
//   A-frag: lane holds A[m=lane&15][k=(lane>>4)*8+i]; B-frag: B[k][n=lane&15]
//   D: lane holds D[row=(lane>>4)*4+r][col=lane&15]
static __device__ __forceinline__ void proj_tile(
    const float* __restrict__ h, const float* __restrict__ W1,
    const float* __restrict__ b1, f16* __restrict__ p,
    int n_nodes, int tile, int lane) {
    const int row0 = tile * 16;
    const int lr = lane & 15;
    const int kg = lane >> 4;

    // B fragments from W1 (row-major [128][32]): 16 KB, L1/L2-resident.
    bf16x8 bfrag[2][4];
#pragma unroll
    for (int ct = 0; ct < 2; ++ct) {
#pragma unroll
        for (int ks = 0; ks < 4; ++ks) {
            const float* wp = W1 + (size_t)(ks * 32 + kg * 8) * HIDDEN + ct * 16 + lr;
#pragma unroll
            for (int i = 0; i < 8; ++i)
                bfrag[ct][ks][i] = f2bf(wp[(size_t)i * HIDDEN]);
        }
    }

    // A fragments from h; clamp row for safety at tails.
    const int arow = (row0 + lr < n_nodes) ? (row0 + lr) : (n_nodes - 1);
    const float* hrow = h + (size_t)arow * IN_FEATS + kg * 8;
    bf16x8 afrag[4];
#pragma unroll
    for (int ks = 0; ks < 4; ++ks) {
        const float4 v0 = *(const float4*)(hrow + ks * 32);
        const float4 v1 = *(const float4*)(hrow + ks * 32 + 4);
        afrag[ks][0] = f2bf(v0.x);
        afrag[ks][1] = f2bf(v0.y);
        afrag[ks][2] = f2bf(v0.z);
        afrag[ks][3] = f2bf(v0.w);
        afrag[ks][4] = f2bf(v1.x);
        afrag[ks][5] = f2bf(v1.y);
        afrag[ks][6] = f2bf(v1.z);
        afrag[ks][7] = f2bf(v1.w);
    }

    // bias rides through the MFMA C-operand (0.5*b1 per endpoint)
    const float hb0 = 0.5f * b1[lr];
    const float hb1 = 0.5f * b1[16 + lr];
    f32x4 acc0 = {hb0, hb0, hb0, hb0};
    f32x4 acc1 = {hb1, hb1, hb1, hb1};
#pragma unroll
    for (int ks = 0; ks < 4; ++ks) {
        acc0 = __builtin_amdgcn_mfma_f32_16x16x32_bf16(afrag[ks], bfrag[0][ks], acc0, 0, 0, 0);
        acc1 = __builtin_amdgcn_mfma_f32_16x16x32_bf16(afrag[ks], bfrag[1][ks], acc1, 0, 0, 0);
    }

    if (row0 + 16 <= n_nodes) {
        f16* prow = p + (size_t)row0 * HIDDEN;
#pragma unroll
        for (int r = 0; r < 4; ++r) {
            prow[(size_t)(kg * 4 + r) * HIDDEN + lr]      = (f16)acc0[r];
            prow[(size_t)(kg * 4 + r) * HIDDEN + 16 + lr] = (f16)acc1[r];
        }
    } else {
#pragma unroll
        for (int r = 0; r < 4; ++r) {
            const int rr = row0 + kg * 4 + r;
            if (rr < n_nodes) {
                p[(size_t)rr * HIDDEN + lr]      = (f16)acc0[r];
                p[(size_t)rr * HIDDEN + 16 + lr] = (f16)acc1[r];
            }
        }
    }
}

// ---- Phase 2 (per 4-edge group, 4 lanes): out = relu(p[s]+p[d]).W2 + b2 ----
static __device__ __forceinline__ void edge_group(
    const f16* __restrict__ p, const int* __restrict__ src,
    const int* __restrict__ dst, const f16x2* w2h, float b2s,
    float* __restrict__ out, int n_edges, int e0, int q) {
    const f16x2 zero2 = f16x2{(f16)0.0f, (f16)0.0f};

    if (e0 + 3 < n_edges) {
        const int4 s4 = *(const int4*)(src + e0);   // broadcast within group
        const int4 d4 = *(const int4*)(dst + e0);

        const f16x8 a0 = *(const f16x8*)(p + (size_t)s4.x * HIDDEN + q * 8);
        const f16x8 a1 = *(const f16x8*)(p + (size_t)s4.y * HIDDEN + q * 8);
        const f16x8 a2 = *(const f16x8*)(p + (size_t)s4.z * HIDDEN + q * 8);
        const f16x8 a3 = *(const f16x8*)(p + (size_t)s4.w * HIDDEN + q * 8);
        const f16x8 c0 = *(const f16x8*)(p + (size_t)d4.x * HIDDEN + q * 8);
        const f16x8 c1 = *(const f16x8*)(p + (size_t)d4.y * HIDDEN + q * 8);
        const f16x8 c2 = *(const f16x8*)(p + (size_t)d4.z * HIDDEN + q * 8);
        const f16x8 c3 = *(const f16x8*)(p + (size_t)d4.w * HIDDEN + q * 8);

        const f16x8 A[4] = {a0, a1, a2, a3};
        const f16x8 C[4] = {c0, c1, c2, c3};

        float res[4];
#pragma unroll
        for (int i = 0; i < 4; ++i) {
            float part = 0.0f;
#pragma unroll
            for (int j = 0; j < 4; ++j) {
                f16x2 av = f16x2{A[i][2 * j], A[i][2 * j + 1]};
                f16x2 cv = f16x2{C[i][2 * j], C[i][2 * j + 1]};
                f16x2 sum = av + cv;                              // v_pk_add_f16
                f16x2 rl = __builtin_elementwise_max(sum, zero2); // v_pk_max_f16
#if __has_builtin(__builtin_amdgcn_fdot2)
                part = __builtin_amdgcn_fdot2(rl, w2h[j], part, false);
#else
                part = fmaf((float)rl[0], (float)w2h[j][0], part);
                part = fmaf((float)rl[1], (float)w2h[j][1], part);
#endif
            }
            part += __shfl_xor(part, 1, 4);
            part += __shfl_xor(part, 2, 4);
            res[i] = part + b2s;
        }
        if (q == 0) *(float4*)(out + e0) = make_float4(res[0], res[1], res[2], res[3]);
    } else {
        for (int i = 0; i < 4 && e0 + i < n_edges; ++i) {
            const int s = src[e0 + i];
            const int d = dst[e0 + i];
            const f16x8 a = *(const f16x8*)(p + (size_t)s * HIDDEN + q * 8);
            const f16x8 c = *(const f16x8*)(p + (size_t)d * HIDDEN + q * 8);
            float part = 0.0f;
#pragma unroll
            for (int j = 0; j < 4; ++j) {
                float s0 = (float)a[2 * j] + (float)c[2 * j];
                float s1 = (float)a[2 * j + 1] + (float)c[2 * j + 1];
                part = fmaf(fmaxf(s0, 0.0f), (float)w2h[j][0], part);
                part = fmaf(fmaxf(s1, 0.0f), (float)w2h[j][1], part);
            }
            part += __shfl_xor(part, 1, 4);
            part += __shfl_xor(part, 2, 4);
            if (q == 0) out[e0 + i] = part + b2s;
        }
    }
}

// ---- Fused cooperative kernel: proj -> grid.sync -> edges ----
__global__ __launch_bounds__(256) void fused_coop_kernel(
    const float* __restrict__ h, const int* __restrict__ src,
    const int* __restrict__ dst, const float* __restrict__ W1,
    const float* __restrict__ b1, const float* __restrict__ W2,
    const float* __restrict__ b2, f16* __restrict__ p,
    float* __restrict__ out, int n_nodes, int n_edges) {
    const int t = threadIdx.x;
    const int lane = t & 63;
    const int wave = t >> 6;
    const int ntiles = (n_nodes + 15) >> 4;

    for (int tile = blockIdx.x * 4 + wave; tile < ntiles; tile += gridDim.x * 4)
        proj_tile(h, W1, b1, p, n_nodes, tile, lane);

    cg::this_grid().sync();   // device-scope release/acquire: p visible cross-XCD

    const int q = t & 3;
    const int slot = t >> 2;
    const float4 w0 = ((const float4*)W2)[q * 2];
    const float4 w1 = ((const float4*)W2)[q * 2 + 1];
    f16x2 w2h[4];
    w2h[0] = f16x2{(f16)w0.x, (f16)w0.y};
    w2h[1] = f16x2{(f16)w0.z, (f16)w0.w};
    w2h[2] = f16x2{(f16)w1.x, (f16)w1.y};
    w2h[3] = f16x2{(f16)w1.z, (f16)w1.w};
    const float b2s = b2[0];

    const int ngroups = (n_edges + 3) >> 2;
    for (int g0 = blockIdx.x * 64; g0 < ngroups; g0 += gridDim.x * 64) {
        const int g = g0 + slot;
        if (g < ngroups)
            edge_group(p, src, dst, w2h, b2s, out, n_edges, g * 4, q);
    }
}

// ---- Fallback two-kernel path (R6-proven) ----
__global__ __launch_bounds__(256) void node_proj_mfma(
    const float* __restrict__ h, const float* __restrict__ W1,
    const float* __restrict__ b1, f16* __restrict__ p, int n_nodes) {
    const int t = threadIdx.x;
    const int tile = blockIdx.x * 4 + (t >> 6);
    if (tile * 16 >= n_nodes) return;
    proj_tile(h, W1, b1, p, n_nodes, tile, t & 63);
}

__global__ __launch_bounds__(256) void edge_mlp_f16(
    const f16* __restrict__ p, const int* __restrict__ src,
    const int* __restrict__ dst, const float* __restrict__ W2,
    const float* __restrict__ b2, float* __restrict__ out, int n_edges) {
    const int t = threadIdx.x;
    const int q = t & 3;
    const int slot = t >> 2;
    const float4 w0 = ((const float4*)W2)[q * 2];
    const float4 w1 = ((const float4*)W2)[q * 2 + 1];
    f16x2 w2h[4];
    w2h[0] = f16x2{(f16)w0.x, (f16)w0.y};
    w2h[1] = f16x2{(f16)w0.z, (f16)w0.w};
    w2h[2] = f16x2{(f16)w1.x, (f16)w1.y};
    w2h[3] = f16x2{(f16)w1.z, (f16)w1.w};
    const float b2s = b2[0];
    const int g = blockIdx.x * 64 + slot;
    if (g * 4 >= n_edges) return;
    edge_group(p, src, dst, w2h, b2s, out, n_edges, g * 4, q);
}

// Fallback if ws too small for p: fully fused per-edge (slow but correct).
__global__ __launch_bounds__(256) void fused_edge_kernel(
    const float* __restrict__ h, const int* __restrict__ src,
    const int* __restrict__ dst, const float* __restrict__ W1,
    const float* __restrict__ b1, const float* __restrict__ W2,
    const float* __restrict__ b2, float* __restrict__ out, int n_edges) {
    __shared__ float W1s[IN_FEATS * HIDDEN];
    __shared__ float sc[8][IN_FEATS];
    const int t = threadIdx.x;
    {
        const float4* W1v = (const float4*)W1;
        float4* W1sv = (float4*)W1s;
#pragma unroll
        for (int i = 0; i < 4; ++i) W1sv[t + i * 256] = W1v[t + i * 256];
    }
    const int le = t >> 5;
    const int j  = t & 31;
    const int e = blockIdx.x * 8 + le;
    __syncthreads();
    if (e < n_edges) {
        const int s = src[e];
        const int d = dst[e];
        const float4* hs4 = (const float4*)(h + (size_t)s * IN_FEATS);
        const float4* hd4 = (const float4*)(h + (size_t)d * IN_FEATS);
        float4* sc4 = (float4*)sc[le];
        float4 a = hs4[j], b = hd4[j];
        sc4[j] = make_float4(a.x + b.x, a.y + b.y, a.z + b.z, a.w + b.w);
    }
    __syncthreads();
    if (e >= n_edges) return;
    float acc = b1[j];
    const float* scp = sc[le];
#pragma unroll
    for (int k = 0; k < IN_FEATS; ++k)
        acc = fmaf(scp[k], W1s[k * HIDDEN + j], acc);
    float hval = fmaxf(acc, 0.0f) * W2[j];
#pragma unroll
    for (int off = 16; off >= 1; off >>= 1)
        hval += __shfl_down(hval, off, 32);
    if (j == 0) out[e] = hval + b2[0];
}

extern "C" void kernel_launch(void* const* d_in, const int* in_sizes, int n_in,
                              void* d_out, int out_size, void* d_ws, size_t ws_size,
                              hipStream_t stream) {
    // setup_inputs() order: h, src, dst, W1, b1, W2, b2
    const float* h   = (const float*)d_in[0];
    const int*   src = (const int*)d_in[1];
    const int*   dst = (const int*)d_in[2];
    const float* W1  = (const float*)d_in[3];
    const float* b1  = (const float*)d_in[4];
    const float* W2  = (const float*)d_in[5];
    const float* b2  = (const float*)d_in[6];
    float* out = (float*)d_out;

    int n_nodes = in_sizes[0] / IN_FEATS;   // 40000
    int n_edges = in_sizes[1];              // 640000

    const size_t p_bytes = (size_t)n_nodes * HIDDEN * sizeof(f16);   // 2.56 MB

    if (ws_size < p_bytes) {
        fused_edge_kernel<<<(n_edges + 7) / 8, 256, 0, stream>>>(
            h, src, dst, W1, b1, W2, b2, out, n_edges);
        return;
    }

    f16* p = (f16*)d_ws;

    // ---- Try single cooperative kernel (removes one launch + serialization) ----
    // Host-side queries only (capture-safe, deterministic).
    int nb = 0;
    hipError_t oq = hipOccupancyMaxActiveBlocksPerMultiprocessor(
        &nb, fused_coop_kernel, 256, 0);
    int cus = 0, dev = 0;
    (void)hipGetDevice(&dev);
    if (hipDeviceGetAttribute(&cus, hipDeviceAttributeMultiprocessorCount, dev)
            != hipSuccess || cus <= 0)
        cus = 256;

    bool coop_ok = false;
    if (oq == hipSuccess && nb > 0) {
        int G = nb * cus;
        const int ngroups = (n_edges + 3) >> 2;
        const int maxG = (ngroups + 63) / 64;
        if (G > maxG) G = maxG;
        if (G > 0) {
            void* args[] = {(void*)&h, (void*)&src, (void*)&dst, (void*)&W1,
                            (void*)&b1, (void*)&W2, (void*)&b2, (void*)&p,
                            (void*)&out, (void*)&n_nodes, (void*)&n_edges};
            hipError_t le = hipLaunchCooperativeKernel(
                (const void*)fused_coop_kernel, dim3(G), dim3(256), args, 0, stream);
            coop_ok = (le == hipSuccess);
        }
    }

    if (!coop_ok) {
        // Proven two-kernel path (R6: 22.8 us)
        const int tiles = (n_nodes + 15) / 16;
        node_proj_mfma<<<(tiles + 3) / 4, 256, 0, stream>>>(h, W1, b1, p, n_nodes);
        const int eblocks = (n_edges + 255) / 256;
        edge_mlp_f16<<<eblocks, 256, 0, stream>>>(p, src, dst, W2, b2, out, n_edges);
    }
}

// Round 10
// 94.817 us; speedup vs baseline: 1.0905x; 1.0905x over previous
//
#include <hip/hip_runtime.h>
#include <hip/hip_bf16.h>

#define IN_FEATS 128
#define HIDDEN 32

typedef __attribute__((ext_vector_type(8))) short bf16x8;   // 8 bf16 (4 VGPRs)
typedef __attribute__((ext_vector_type(4))) float f32x4;
typedef _Float16 f16;
typedef __attribute__((ext_vector_type(2))) _Float16 f16x2;
typedef __attribute__((ext_vector_type(8))) _Float16 f16x8; // 16 B

// fp32 -> bf16 round-to-nearest-even (bit trick; NaN irrelevant for this data)
static __device__ __forceinline__ short f2bf(float f) {
    union { float f; unsigned u; } v;
    v.f = f;
    unsigned r = v.u + 0x7FFFu + ((v.u >> 16) & 1u);
    return (short)(r >> 16);
}

// ---- Phase 1 (per 16-row tile, one wave): p[tile] = fp16(h @ W1 + 0.5*b1) ----
// Verified gfx950 16x16x32 bf16 layouts (learn_hip m89/m91):
//   A-frag: lane holds A[m=lane&15][k=(lane>>4)*8+i]; B-frag: B[k][n=lane&15]
//   D: lane holds D[row=(lane>>4)*4+r][col=lane&15]
static __device__ __forceinline__ void proj_tile(
    const float* __restrict__ h, const float* __restrict__ W1,
    const float* __restrict__ b1, f16* __restrict__ p,
    int n_nodes, int tile, int lane) {
    const int row0 = tile * 16;
    const int lr = lane & 15;
    const int kg = lane >> 4;

    // B fragments from W1 (row-major [128][32]): 16 KB, L1/L2-resident.
    bf16x8 bfrag[2][4];
#pragma unroll
    for (int ct = 0; ct < 2; ++ct) {
#pragma unroll
        for (int ks = 0; ks < 4; ++ks) {
            const float* wp = W1 + (size_t)(ks * 32 + kg * 8) * HIDDEN + ct * 16 + lr;
#pragma unroll
            for (int i = 0; i < 8; ++i)
                bfrag[ct][ks][i] = f2bf(wp[(size_t)i * HIDDEN]);
        }
    }

    // A fragments from h; clamp row for safety at tails.
    const int arow = (row0 + lr < n_nodes) ? (row0 + lr) : (n_nodes - 1);
    const float* hrow = h + (size_t)arow * IN_FEATS + kg * 8;
    bf16x8 afrag[4];
#pragma unroll
    for (int ks = 0; ks < 4; ++ks) {
        const float4 v0 = *(const float4*)(hrow + ks * 32);
        const float4 v1 = *(const float4*)(hrow + ks * 32 + 4);
        afrag[ks][0] = f2bf(v0.x);
        afrag[ks][1] = f2bf(v0.y);
        afrag[ks][2] = f2bf(v0.z);
        afrag[ks][3] = f2bf(v0.w);
        afrag[ks][4] = f2bf(v1.x);
        afrag[ks][5] = f2bf(v1.y);
        afrag[ks][6] = f2bf(v1.z);
        afrag[ks][7] = f2bf(v1.w);
    }

    // bias rides through the MFMA C-operand (0.5*b1 per endpoint)
    const float hb0 = 0.5f * b1[lr];
    const float hb1 = 0.5f * b1[16 + lr];
    f32x4 acc0 = {hb0, hb0, hb0, hb0};
    f32x4 acc1 = {hb1, hb1, hb1, hb1};
#pragma unroll
    for (int ks = 0; ks < 4; ++ks) {
        acc0 = __builtin_amdgcn_mfma_f32_16x16x32_bf16(afrag[ks], bfrag[0][ks], acc0, 0, 0, 0);
        acc1 = __builtin_amdgcn_mfma_f32_16x16x32_bf16(afrag[ks], bfrag[1][ks], acc1, 0, 0, 0);
    }

    if (row0 + 16 <= n_nodes) {
        f16* prow = p + (size_t)row0 * HIDDEN;
#pragma unroll
        for (int r = 0; r < 4; ++r) {
            prow[(size_t)(kg * 4 + r) * HIDDEN + lr]      = (f16)acc0[r];
            prow[(size_t)(kg * 4 + r) * HIDDEN + 16 + lr] = (f16)acc1[r];
        }
    } else {
#pragma unroll
        for (int r = 0; r < 4; ++r) {
            const int rr = row0 + kg * 4 + r;
            if (rr < n_nodes) {
                p[(size_t)rr * HIDDEN + lr]      = (f16)acc0[r];
                p[(size_t)rr * HIDDEN + 16 + lr] = (f16)acc1[r];
            }
        }
    }
}

// ---- Phase 2 (per 4-edge group, 4 lanes): out = relu(p[s]+p[d]).W2 + b2 ----
static __device__ __forceinline__ void edge_group(
    const f16* __restrict__ p, const int* __restrict__ src,
    const int* __restrict__ dst, const f16x2* w2h, float b2s,
    float* __restrict__ out, int n_edges, int e0, int q) {
    const f16x2 zero2 = f16x2{(f16)0.0f, (f16)0.0f};

    if (e0 + 3 < n_edges) {
        const int4 s4 = *(const int4*)(src + e0);   // broadcast within group
        const int4 d4 = *(const int4*)(dst + e0);

        const f16x8 a0 = *(const f16x8*)(p + (size_t)s4.x * HIDDEN + q * 8);
        const f16x8 a1 = *(const f16x8*)(p + (size_t)s4.y * HIDDEN + q * 8);
        const f16x8 a2 = *(const f16x8*)(p + (size_t)s4.z * HIDDEN + q * 8);
        const f16x8 a3 = *(const f16x8*)(p + (size_t)s4.w * HIDDEN + q * 8);
        const f16x8 c0 = *(const f16x8*)(p + (size_t)d4.x * HIDDEN + q * 8);
        const f16x8 c1 = *(const f16x8*)(p + (size_t)d4.y * HIDDEN + q * 8);
        const f16x8 c2 = *(const f16x8*)(p + (size_t)d4.z * HIDDEN + q * 8);
        const f16x8 c3 = *(const f16x8*)(p + (size_t)d4.w * HIDDEN + q * 8);

        const f16x8 A[4] = {a0, a1, a2, a3};
        const f16x8 C[4] = {c0, c1, c2, c3};

        float res[4];
#pragma unroll
        for (int i = 0; i < 4; ++i) {
            float part = 0.0f;
#pragma unroll
            for (int j = 0; j < 4; ++j) {
                f16x2 av = f16x2{A[i][2 * j], A[i][2 * j + 1]};
                f16x2 cv = f16x2{C[i][2 * j], C[i][2 * j + 1]};
                f16x2 sum = av + cv;                              // v_pk_add_f16
                f16x2 rl = __builtin_elementwise_max(sum, zero2); // v_pk_max_f16
#if __has_builtin(__builtin_amdgcn_fdot2)
                part = __builtin_amdgcn_fdot2(rl, w2h[j], part, false);
#else
                part = fmaf((float)rl[0], (float)w2h[j][0], part);
                part = fmaf((float)rl[1], (float)w2h[j][1], part);
#endif
            }
            part += __shfl_xor(part, 1, 4);
            part += __shfl_xor(part, 2, 4);
            res[i] = part + b2s;
        }
        if (q == 0) *(float4*)(out + e0) = make_float4(res[0], res[1], res[2], res[3]);
    } else {
        for (int i = 0; i < 4 && e0 + i < n_edges; ++i) {
            const int s = src[e0 + i];
            const int d = dst[e0 + i];
            const f16x8 a = *(const f16x8*)(p + (size_t)s * HIDDEN + q * 8);
            const f16x8 c = *(const f16x8*)(p + (size_t)d * HIDDEN + q * 8);
            float part = 0.0f;
#pragma unroll
            for (int j = 0; j < 4; ++j) {
                float s0 = (float)a[2 * j] + (float)c[2 * j];
                float s1 = (float)a[2 * j + 1] + (float)c[2 * j + 1];
                part = fmaf(fmaxf(s0, 0.0f), (float)w2h[j][0], part);
                part = fmaf(fmaxf(s1, 0.0f), (float)w2h[j][1], part);
            }
            part += __shfl_xor(part, 1, 4);
            part += __shfl_xor(part, 2, 4);
            if (q == 0) out[e0 + i] = part + b2s;
        }
    }
}

// ---- Fused kernel with hand-rolled device barrier (no cg::sync) ----
// All blocks co-resident (grid sized from occupancy API). Release: syncthreads
// -> tid0 threadfence (agent) + atomicAdd. Acquire: tid0 spins on ACQUIRE load
// with s_sleep polls -> syncthreads.
__global__ __launch_bounds__(256) void fused_flag_kernel(
    const float* __restrict__ h, const int* __restrict__ src,
    const int* __restrict__ dst, const float* __restrict__ W1,
    const float* __restrict__ b1, const float* __restrict__ W2,
    const float* __restrict__ b2, f16* __restrict__ p,
    unsigned int* __restrict__ counter,
    float* __restrict__ out, int n_nodes, int n_edges) {
    const int t = threadIdx.x;
    const int lane = t & 63;
    const int wave = t >> 6;
    const int ntiles = (n_nodes + 15) >> 4;

    // ---- phase 1: projection (grid-stride over 16-row tiles) ----
    for (int tile = blockIdx.x * 4 + wave; tile < ntiles; tile += gridDim.x * 4)
        proj_tile(h, W1, b1, p, n_nodes, tile, lane);

    // ---- device barrier ----
    __syncthreads();                    // block's proj stores all issued
    if (t == 0) {
        __threadfence();                // agent-scope release of p stores
        __hip_atomic_fetch_add(counter, 1u, __ATOMIC_ACQ_REL,
                               __HIP_MEMORY_SCOPE_AGENT);
        while (__hip_atomic_load(counter, __ATOMIC_ACQUIRE,
                                 __HIP_MEMORY_SCOPE_AGENT) < gridDim.x)
            __builtin_amdgcn_s_sleep(8);
        __threadfence();                // acquire side
    }
    __syncthreads();

    // ---- phase 2: edge MLP (grid-stride over 4-edge groups) ----
    const int q = t & 3;
    const int slot = t >> 2;
    const float4 w0 = ((const float4*)W2)[q * 2];
    const float4 w1 = ((const float4*)W2)[q * 2 + 1];
    f16x2 w2h[4];
    w2h[0] = f16x2{(f16)w0.x, (f16)w0.y};
    w2h[1] = f16x2{(f16)w0.z, (f16)w0.w};
    w2h[2] = f16x2{(f16)w1.x, (f16)w1.y};
    w2h[3] = f16x2{(f16)w1.z, (f16)w1.w};
    const float b2s = b2[0];

    const int ngroups = (n_edges + 3) >> 2;
    for (int g0 = blockIdx.x * 64; g0 < ngroups; g0 += gridDim.x * 64) {
        const int g = g0 + slot;
        if (g < ngroups)
            edge_group(p, src, dst, w2h, b2s, out, n_edges, g * 4, q);
    }
}

// ---- Proven two-kernel path (R6: 22.8 us) ----
__global__ __launch_bounds__(256) void node_proj_mfma(
    const float* __restrict__ h, const float* __restrict__ W1,
    const float* __restrict__ b1, f16* __restrict__ p, int n_nodes) {
    const int t = threadIdx.x;
    const int tile = blockIdx.x * 4 + (t >> 6);
    if (tile * 16 >= n_nodes) return;
    proj_tile(h, W1, b1, p, n_nodes, tile, t & 63);
}

__global__ __launch_bounds__(256) void edge_mlp_f16(
    const f16* __restrict__ p, const int* __restrict__ src,
    const int* __restrict__ dst, const float* __restrict__ W2,
    const float* __restrict__ b2, float* __restrict__ out, int n_edges) {
    const int t = threadIdx.x;
    const int q = t & 3;
    const int slot = t >> 2;
    const float4 w0 = ((const float4*)W2)[q * 2];
    const float4 w1 = ((const float4*)W2)[q * 2 + 1];
    f16x2 w2h[4];
    w2h[0] = f16x2{(f16)w0.x, (f16)w0.y};
    w2h[1] = f16x2{(f16)w0.z, (f16)w0.w};
    w2h[2] = f16x2{(f16)w1.x, (f16)w1.y};
    w2h[3] = f16x2{(f16)w1.z, (f16)w1.w};
    const float b2s = b2[0];
    const int g = blockIdx.x * 64 + slot;
    if (g * 4 >= n_edges) return;
    edge_group(p, src, dst, w2h, b2s, out, n_edges, g * 4, q);
}

// Fallback if ws too small for p: fully fused per-edge (slow but correct).
__global__ __launch_bounds__(256) void fused_edge_kernel(
    const float* __restrict__ h, const int* __restrict__ src,
    const int* __restrict__ dst, const float* __restrict__ W1,
    const float* __restrict__ b1, const float* __restrict__ W2,
    const float* __restrict__ b2, float* __restrict__ out, int n_edges) {
    __shared__ float W1s[IN_FEATS * HIDDEN];
    __shared__ float sc[8][IN_FEATS];
    const int t = threadIdx.x;
    {
        const float4* W1v = (const float4*)W1;
        float4* W1sv = (float4*)W1s;
#pragma unroll
        for (int i = 0; i < 4; ++i) W1sv[t + i * 256] = W1v[t + i * 256];
    }
    const int le = t >> 5;
    const int j  = t & 31;
    const int e = blockIdx.x * 8 + le;
    __syncthreads();
    if (e < n_edges) {
        const int s = src[e];
        const int d = dst[e];
        const float4* hs4 = (const float4*)(h + (size_t)s * IN_FEATS);
        const float4* hd4 = (const float4*)(h + (size_t)d * IN_FEATS);
        float4* sc4 = (float4*)sc[le];
        float4 a = hs4[j], b = hd4[j];
        sc4[j] = make_float4(a.x + b.x, a.y + b.y, a.z + b.z, a.w + b.w);
    }
    __syncthreads();
    if (e >= n_edges) return;
    float acc = b1[j];
    const float* scp = sc[le];
#pragma unroll
    for (int k = 0; k < IN_FEATS; ++k)
        acc = fmaf(scp[k], W1s[k * HIDDEN + j], acc);
    float hval = fmaxf(acc, 0.0f) * W2[j];
#pragma unroll
    for (int off = 16; off >= 1; off >>= 1)
        hval += __shfl_down(hval, off, 32);
    if (j == 0) out[e] = hval + b2[0];
}

extern "C" void kernel_launch(void* const* d_in, const int* in_sizes, int n_in,
                              void* d_out, int out_size, void* d_ws, size_t ws_size,
                              hipStream_t stream) {
    // setup_inputs() order: h, src, dst, W1, b1, W2, b2
    const float* h   = (const float*)d_in[0];
    const int*   src = (const int*)d_in[1];
    const int*   dst = (const int*)d_in[2];
    const float* W1  = (const float*)d_in[3];
    const float* b1  = (const float*)d_in[4];
    const float* W2  = (const float*)d_in[5];
    const float* b2  = (const float*)d_in[6];
    float* out = (float*)d_out;

    int n_nodes = in_sizes[0] / IN_FEATS;   // 40000
    int n_edges = in_sizes[1];              // 640000

    // ws layout: [0,256) counter cell, [256, 256 + p_bytes) fp16 p
    const size_t p_bytes = (size_t)n_nodes * HIDDEN * sizeof(f16);   // 2.56 MB

    if (ws_size < p_bytes + 256) {
        fused_edge_kernel<<<(n_edges + 7) / 8, 256, 0, stream>>>(
            h, src, dst, W1, b1, W2, b2, out, n_edges);
        return;
    }

    unsigned int* counter = (unsigned int*)d_ws;
    f16* p = (f16*)((char*)d_ws + 256);

    // Grid must be <= co-resident capacity for the hand-rolled barrier.
    int nb = 0;
    hipError_t oq = hipOccupancyMaxActiveBlocksPerMultiprocessor(
        &nb, fused_flag_kernel, 256, 0);
    int cus = 0, dev = 0;
    (void)hipGetDevice(&dev);
    if (hipDeviceGetAttribute(&cus, hipDeviceAttributeMultiprocessorCount, dev)
            != hipSuccess || cus <= 0)
        cus = 256;

    if (oq == hipSuccess && nb > 0) {
        int G = nb * cus;
        if (G > 2500) G = 2500;   // enough for all edge groups in one stride
        // reset barrier counter each call (graph-capturable memset node)
        (void)hipMemsetAsync(counter, 0, sizeof(unsigned int), stream);
        fused_flag_kernel<<<G, 256, 0, stream>>>(
            h, src, dst, W1, b1, W2, b2, p, counter, out, n_nodes, n_edges);
    } else {
        const int tiles = (n_nodes + 15) / 16;
        node_proj_mfma<<<(tiles + 3) / 4, 256, 0, stream>>>(h, W1, b1, p, n_nodes);
        const int eblocks = (n_edges + 255) / 256;
        edge_mlp_f16<<<eblocks, 256, 0, stream>>>(p, src, dst, W2, b2, out, n_edges);
    }
}

// Round 11
// 56.501 us; speedup vs baseline: 1.8300x; 1.6781x over previous
//
#include <hip/hip_runtime.h>
#include <hip/hip_bf16.h>

#define IN_FEATS 128
#define HIDDEN 32

typedef __attribute__((ext_vector_type(8))) short bf16x8;   // 8 bf16 (4 VGPRs)
typedef __attribute__((ext_vector_type(4))) float f32x4;
typedef _Float16 f16;
typedef __attribute__((ext_vector_type(2))) _Float16 f16x2;
typedef __attribute__((ext_vector_type(8))) _Float16 f16x8; // 16 B

// fp32 -> bf16 round-to-nearest-even (bit trick; NaN irrelevant for this data)
static __device__ __forceinline__ short f2bf(float f) {
    union { float f; unsigned u; } v;
    v.f = f;
    unsigned r = v.u + 0x7FFFu + ((v.u >> 16) & 1u);
    return (short)(r >> 16);
}

// ---- Phase 1 (per 16-row tile, one wave): p[tile] = fp16(h @ W1 + 0.5*b1) ----
// Verified gfx950 16x16x32 bf16 layouts (learn_hip m89/m91):
//   A-frag: lane holds A[m=lane&15][k=(lane>>4)*8+i]; B-frag: B[k][n=lane&15]
//   D: lane holds D[row=(lane>>4)*4+r][col=lane&15]
static __device__ __forceinline__ void proj_tile(
    const float* __restrict__ h, const float* __restrict__ W1,
    const float* __restrict__ b1, f16* __restrict__ p,
    int n_nodes, int tile, int lane) {
    const int row0 = tile * 16;
    const int lr = lane & 15;
    const int kg = lane >> 4;

    // B fragments from W1 (row-major [128][32]): 16 KB, L1/L2-resident.
    bf16x8 bfrag[2][4];
#pragma unroll
    for (int ct = 0; ct < 2; ++ct) {
#pragma unroll
        for (int ks = 0; ks < 4; ++ks) {
            const float* wp = W1 + (size_t)(ks * 32 + kg * 8) * HIDDEN + ct * 16 + lr;
#pragma unroll
            for (int i = 0; i < 8; ++i)
                bfrag[ct][ks][i] = f2bf(wp[(size_t)i * HIDDEN]);
        }
    }

    // A fragments from h; clamp row for safety at tails.
    const int arow = (row0 + lr < n_nodes) ? (row0 + lr) : (n_nodes - 1);
    const float* hrow = h + (size_t)arow * IN_FEATS + kg * 8;
    bf16x8 afrag[4];
#pragma unroll
    for (int ks = 0; ks < 4; ++ks) {
        const float4 v0 = *(const float4*)(hrow + ks * 32);
        const float4 v1 = *(const float4*)(hrow + ks * 32 + 4);
        afrag[ks][0] = f2bf(v0.x);
        afrag[ks][1] = f2bf(v0.y);
        afrag[ks][2] = f2bf(v0.z);
        afrag[ks][3] = f2bf(v0.w);
        afrag[ks][4] = f2bf(v1.x);
        afrag[ks][5] = f2bf(v1.y);
        afrag[ks][6] = f2bf(v1.z);
        afrag[ks][7] = f2bf(v1.w);
    }

    // bias rides through the MFMA C-operand (0.5*b1 per endpoint)
    const float hb0 = 0.5f * b1[lr];
    const float hb1 = 0.5f * b1[16 + lr];
    f32x4 acc0 = {hb0, hb0, hb0, hb0};
    f32x4 acc1 = {hb1, hb1, hb1, hb1};
#pragma unroll
    for (int ks = 0; ks < 4; ++ks) {
        acc0 = __builtin_amdgcn_mfma_f32_16x16x32_bf16(afrag[ks], bfrag[0][ks], acc0, 0, 0, 0);
        acc1 = __builtin_amdgcn_mfma_f32_16x16x32_bf16(afrag[ks], bfrag[1][ks], acc1, 0, 0, 0);
    }

    if (row0 + 16 <= n_nodes) {
        f16* prow = p + (size_t)row0 * HIDDEN;
#pragma unroll
        for (int r = 0; r < 4; ++r) {
            prow[(size_t)(kg * 4 + r) * HIDDEN + lr]      = (f16)acc0[r];
            prow[(size_t)(kg * 4 + r) * HIDDEN + 16 + lr] = (f16)acc1[r];
        }
    } else {
#pragma unroll
        for (int r = 0; r < 4; ++r) {
            const int rr = row0 + kg * 4 + r;
            if (rr < n_nodes) {
                p[(size_t)rr * HIDDEN + lr]      = (f16)acc0[r];
                p[(size_t)rr * HIDDEN + 16 + lr] = (f16)acc1[r];
            }
        }
    }
}

// ---- Phase 2 (per 4-edge group, 4 lanes): out = relu(p[s]+p[d]).W2 + b2 ----
static __device__ __forceinline__ void edge_group(
    const f16* __restrict__ p, const int* __restrict__ src,
    const int* __restrict__ dst, const f16x2* w2h, float b2s,
    float* __restrict__ out, int n_edges, int e0, int q) {
    const f16x2 zero2 = f16x2{(f16)0.0f, (f16)0.0f};

    if (e0 + 3 < n_edges) {
        const int4 s4 = *(const int4*)(src + e0);   // broadcast within group
        const int4 d4 = *(const int4*)(dst + e0);

        const f16x8 a0 = *(const f16x8*)(p + (size_t)s4.x * HIDDEN + q * 8);
        const f16x8 a1 = *(const f16x8*)(p + (size_t)s4.y * HIDDEN + q * 8);
        const f16x8 a2 = *(const f16x8*)(p + (size_t)s4.z * HIDDEN + q * 8);
        const f16x8 a3 = *(const f16x8*)(p + (size_t)s4.w * HIDDEN + q * 8);
        const f16x8 c0 = *(const f16x8*)(p + (size_t)d4.x * HIDDEN + q * 8);
        const f16x8 c1 = *(const f16x8*)(p + (size_t)d4.y * HIDDEN + q * 8);
        const f16x8 c2 = *(const f16x8*)(p + (size_t)d4.z * HIDDEN + q * 8);
        const f16x8 c3 = *(const f16x8*)(p + (size_t)d4.w * HIDDEN + q * 8);

        const f16x8 A[4] = {a0, a1, a2, a3};
        const f16x8 C[4] = {c0, c1, c2, c3};

        float res[4];
#pragma unroll
        for (int i = 0; i < 4; ++i) {
            float part = 0.0f;
#pragma unroll
            for (int j = 0; j < 4; ++j) {
                f16x2 av = f16x2{A[i][2 * j], A[i][2 * j + 1]};
                f16x2 cv = f16x2{C[i][2 * j], C[i][2 * j + 1]};
                f16x2 sum = av + cv;                              // v_pk_add_f16
                f16x2 rl = __builtin_elementwise_max(sum, zero2); // v_pk_max_f16
#if __has_builtin(__builtin_amdgcn_fdot2)
                part = __builtin_amdgcn_fdot2(rl, w2h[j], part, false);
#else
                part = fmaf((float)rl[0], (float)w2h[j][0], part);
                part = fmaf((float)rl[1], (float)w2h[j][1], part);
#endif
            }
            part += __shfl_xor(part, 1, 4);
            part += __shfl_xor(part, 2, 4);
            res[i] = part + b2s;
        }
        if (q == 0) *(float4*)(out + e0) = make_float4(res[0], res[1], res[2], res[3]);
    } else {
        for (int i = 0; i < 4 && e0 + i < n_edges; ++i) {
            const int s = src[e0 + i];
            const int d = dst[e0 + i];
            const f16x8 a = *(const f16x8*)(p + (size_t)s * HIDDEN + q * 8);
            const f16x8 c = *(const f16x8*)(p + (size_t)d * HIDDEN + q * 8);
            float part = 0.0f;
#pragma unroll
            for (int j = 0; j < 4; ++j) {
                float s0 = (float)a[2 * j] + (float)c[2 * j];
                float s1 = (float)a[2 * j + 1] + (float)c[2 * j + 1];
                part = fmaf(fmaxf(s0, 0.0f), (float)w2h[j][0], part);
                part = fmaf(fmaxf(s1, 0.0f), (float)w2h[j][1], part);
            }
            part += __shfl_xor(part, 1, 4);
            part += __shfl_xor(part, 2, 4);
            if (q == 0) out[e0 + i] = part + b2s;
        }
    }
}

// Barrier region layout (uint offsets within the 32 KB ws prefix):
//   go   @ bar[0]         (own 256 B line, read-only polled)
//   root @ bar[64]        (own 256 B line, 64 RMWs total)
//   leaf i @ bar[128+64*i] (64 leaves, 256 B apart, G/64 RMWs each)
#define BAR_UINTS_GO   0
#define BAR_UINTS_ROOT 64
#define BAR_UINTS_LEAF 128

// ---- Fused kernel with contention-free two-level device barrier ----
__global__ __launch_bounds__(256) void fused_tree_kernel(
    const float* __restrict__ h, const int* __restrict__ src,
    const int* __restrict__ dst, const float* __restrict__ W1,
    const float* __restrict__ b1, const float* __restrict__ W2,
    const float* __restrict__ b2, f16* __restrict__ p,
    unsigned int* bar,
    float* __restrict__ out, int n_nodes, int n_edges) {
    const int t = threadIdx.x;
    const int lane = t & 63;
    const int wave = t >> 6;
    const int ntiles = (n_nodes + 15) >> 4;

    // ---- phase 1: projection (grid-stride over 16-row tiles) ----
    for (int tile = blockIdx.x * 4 + wave; tile < ntiles; tile += gridDim.x * 4)
        proj_tile(h, W1, b1, p, n_nodes, tile, lane);

    // ---- device barrier: tree arrivals, separate release flag ----
    __syncthreads();
    if (t == 0) {
        __threadfence();   // release: p stores -> device scope
        const unsigned int leaf_n = gridDim.x >> 6;   // G is a multiple of 64
        unsigned int* leaf = bar + BAR_UINTS_LEAF + (blockIdx.x & 63) * 64;
        const unsigned int lv = __hip_atomic_fetch_add(
            leaf, 1u, __ATOMIC_RELAXED, __HIP_MEMORY_SCOPE_AGENT);
        if (lv == leaf_n - 1) {                        // last arrival on this leaf
            const unsigned int rv = __hip_atomic_fetch_add(
                bar + BAR_UINTS_ROOT, 1u, __ATOMIC_RELAXED, __HIP_MEMORY_SCOPE_AGENT);
            if (rv == 63) {                            // last leaf
                __hip_atomic_store(bar + BAR_UINTS_GO, 1u,
                                   __ATOMIC_RELEASE, __HIP_MEMORY_SCOPE_AGENT);
            }
        }
        while (__hip_atomic_load(bar + BAR_UINTS_GO, __ATOMIC_RELAXED,
                                 __HIP_MEMORY_SCOPE_AGENT) == 0)
            __builtin_amdgcn_s_sleep(1);
        __threadfence();   // acquire: invalidate stale caches before p gathers
    }
    __syncthreads();

    // ---- phase 2: edge MLP (grid-stride over 4-edge groups) ----
    const int q = t & 3;
    const int slot = t >> 2;
    const float4 w0 = ((const float4*)W2)[q * 2];
    const float4 w1 = ((const float4*)W2)[q * 2 + 1];
    f16x2 w2h[4];
    w2h[0] = f16x2{(f16)w0.x, (f16)w0.y};
    w2h[1] = f16x2{(f16)w0.z, (f16)w0.w};
    w2h[2] = f16x2{(f16)w1.x, (f16)w1.y};
    w2h[3] = f16x2{(f16)w1.z, (f16)w1.w};
    const float b2s = b2[0];

    const int ngroups = (n_edges + 3) >> 2;
    for (int g0 = blockIdx.x * 64; g0 < ngroups; g0 += gridDim.x * 64) {
        const int g = g0 + slot;
        if (g < ngroups)
            edge_group(p, src, dst, w2h, b2s, out, n_edges, g * 4, q);
    }
}

// ---- Proven two-kernel path (R6: 22.8 us) ----
__global__ __launch_bounds__(256) void node_proj_mfma(
    const float* __restrict__ h, const float* __restrict__ W1,
    const float* __restrict__ b1, f16* __restrict__ p, int n_nodes) {
    const int t = threadIdx.x;
    const int tile = blockIdx.x * 4 + (t >> 6);
    if (tile * 16 >= n_nodes) return;
    proj_tile(h, W1, b1, p, n_nodes, tile, t & 63);
}

__global__ __launch_bounds__(256) void edge_mlp_f16(
    const f16* __restrict__ p, const int* __restrict__ src,
    const int* __restrict__ dst, const float* __restrict__ W2,
    const float* __restrict__ b2, float* __restrict__ out, int n_edges) {
    const int t = threadIdx.x;
    const int q = t & 3;
    const int slot = t >> 2;
    const float4 w0 = ((const float4*)W2)[q * 2];
    const float4 w1 = ((const float4*)W2)[q * 2 + 1];
    f16x2 w2h[4];
    w2h[0] = f16x2{(f16)w0.x, (f16)w0.y};
    w2h[1] = f16x2{(f16)w0.z, (f16)w0.w};
    w2h[2] = f16x2{(f16)w1.x, (f16)w1.y};
    w2h[3] = f16x2{(f16)w1.z, (f16)w1.w};
    const float b2s = b2[0];
    const int g = blockIdx.x * 64 + slot;
    if (g * 4 >= n_edges) return;
    edge_group(p, src, dst, w2h, b2s, out, n_edges, g * 4, q);
}

// Fallback if ws too small for p: fully fused per-edge (slow but correct).
__global__ __launch_bounds__(256) void fused_edge_kernel(
    const float* __restrict__ h, const int* __restrict__ src,
    const int* __restrict__ dst, const float* __restrict__ W1,
    const float* __restrict__ b1, const float* __restrict__ W2,
    const float* __restrict__ b2, float* __restrict__ out, int n_edges) {
    __shared__ float W1s[IN_FEATS * HIDDEN];
    __shared__ float sc[8][IN_FEATS];
    const int t = threadIdx.x;
    {
        const float4* W1v = (const float4*)W1;
        float4* W1sv = (float4*)W1s;
#pragma unroll
        for (int i = 0; i < 4; ++i) W1sv[t + i * 256] = W1v[t + i * 256];
    }
    const int le = t >> 5;
    const int j  = t & 31;
    const int e = blockIdx.x * 8 + le;
    __syncthreads();
    if (e < n_edges) {
        const int s = src[e];
        const int d = dst[e];
        const float4* hs4 = (const float4*)(h + (size_t)s * IN_FEATS);
        const float4* hd4 = (const float4*)(h + (size_t)d * IN_FEATS);
        float4* sc4 = (float4*)sc[le];
        float4 a = hs4[j], b = hd4[j];
        sc4[j] = make_float4(a.x + b.x, a.y + b.y, a.z + b.z, a.w + b.w);
    }
    __syncthreads();
    if (e >= n_edges) return;
    float acc = b1[j];
    const float* scp = sc[le];
#pragma unroll
    for (int k = 0; k < IN_FEATS; ++k)
        acc = fmaf(scp[k], W1s[k * HIDDEN + j], acc);
    float hval = fmaxf(acc, 0.0f) * W2[j];
#pragma unroll
    for (int off = 16; off >= 1; off >>= 1)
        hval += __shfl_down(hval, off, 32);
    if (j == 0) out[e] = hval + b2[0];
}

extern "C" void kernel_launch(void* const* d_in, const int* in_sizes, int n_in,
                              void* d_out, int out_size, void* d_ws, size_t ws_size,
                              hipStream_t stream) {
    // setup_inputs() order: h, src, dst, W1, b1, W2, b2
    const float* h   = (const float*)d_in[0];
    const int*   src = (const int*)d_in[1];
    const int*   dst = (const int*)d_in[2];
    const float* W1  = (const float*)d_in[3];
    const float* b1  = (const float*)d_in[4];
    const float* W2  = (const float*)d_in[5];
    const float* b2  = (const float*)d_in[6];
    float* out = (float*)d_out;

    int n_nodes = in_sizes[0] / IN_FEATS;   // 40000
    int n_edges = in_sizes[1];              // 640000

    // ws layout: [0, 32KB) barrier region, [32KB, 32KB + p_bytes) fp16 p
    const size_t BAR_BYTES = 32768;
    const size_t p_bytes = (size_t)n_nodes * HIDDEN * sizeof(f16);   // 2.56 MB

    if (ws_size < p_bytes + BAR_BYTES) {
        fused_edge_kernel<<<(n_edges + 7) / 8, 256, 0, stream>>>(
            h, src, dst, W1, b1, W2, b2, out, n_edges);
        return;
    }

    unsigned int* bar = (unsigned int*)d_ws;
    f16* p = (f16*)((char*)d_ws + BAR_BYTES);

    // Grid must be co-resident for the device barrier; multiple of 64 for the tree.
    int nb = 0;
    hipError_t oq = hipOccupancyMaxActiveBlocksPerMultiprocessor(
        &nb, fused_tree_kernel, 256, 0);
    int cus = 0, dev = 0;
    (void)hipGetDevice(&dev);
    if (hipDeviceGetAttribute(&cus, hipDeviceAttributeMultiprocessorCount, dev)
            != hipSuccess || cus <= 0)
        cus = 256;

    int G = 0;
    if (oq == hipSuccess && nb > 0) {
        G = nb * cus;
        if (G > 2048) G = 2048;
        G &= ~63;                      // multiple of 64 (leaf tree invariant)
    }

    if (G >= 64) {
        // reset barrier region each call (graph-capturable memset node)
        (void)hipMemsetAsync(bar, 0, BAR_BYTES, stream);
        fused_tree_kernel<<<G, 256, 0, stream>>>(
            h, src, dst, W1, b1, W2, b2, p, bar, out, n_nodes, n_edges);
    } else {
        const int tiles = (n_nodes + 15) / 16;
        node_proj_mfma<<<(tiles + 3) / 4, 256, 0, stream>>>(h, W1, b1, p, n_nodes);
        const int eblocks = (n_edges + 255) / 256;
        edge_mlp_f16<<<eblocks, 256, 0, stream>>>(p, src, dst, W2, b2, out, n_edges);
    }
}